// Round 11
// baseline (9912.242 us; speedup 1.0000x reference)
//
#include <hip/hip_runtime.h>
#include <stdint.h>

typedef unsigned short u16;

#define T_STEPS 512
#define BATCH   64
#define DIN     512
#define HID     1024
#define G4      4096
#define THREADS 512
#define NBLK    64      // 64 col-blocks, each owns 16 units (64 gate-cols)
#define UPB     16
// block col c = u_local*4 + gate  <->  gcol = gate*1024 + nb*16 + u_local
// pre-transposed weight row p = (gcol & 1023)*4 + (gcol >> 10) = nb*64 + c

// ws map
#define XB_BYTES  ((size_t)T_STEPS * BATCH * DIN * 2)     // 32 MB bf16 x
#define WPR_OFF   XB_BYTES                                // wpr bf16 [4096][512] = 4 MB
#define WPR_BYTES ((size_t)4096 * 512 * 2)
#define UPR_OFF   (WPR_OFF + WPR_BYTES)                   // upr bf16 [4096][1024] = 8 MB
#define UPR_BYTES ((size_t)4096 * 1024 * 2)
#define TH_OFF    (UPR_OFF + UPR_BYTES)                   // tagged h: [ch2][par2][row32][unit1024] u32
#define TH_BYTES  ((size_t)2 * 2 * 32 * 1024 * 4)         // 512 KB
#define WS_NEED   (TH_OFF + TH_BYTES)

typedef float f32x16 __attribute__((ext_vector_type(16)));
typedef short bf16x8 __attribute__((ext_vector_type(8)));
typedef unsigned uint32x4 __attribute__((ext_vector_type(4)));

__device__ __forceinline__ u16 f2bf(float f) {
  unsigned u = __float_as_uint(f);
  u += 0x7fffu + ((u >> 16) & 1u);   // RNE
  return (u16)(u >> 16);
}
__device__ __forceinline__ float sigm(float x) {
  return __builtin_amdgcn_rcpf(1.f + __expf(-x));
}
__device__ __forceinline__ float fast_tanh(float x) {
  return 1.f - 2.f * __builtin_amdgcn_rcpf(__expf(2.f * x) + 1.f);
}

// Coherent (L2-bypass, coherence-point) helpers; flat 64b VGPR address.
__device__ __forceinline__ uint32x4 load16_sc(uint64_t addr) {
  uint32x4 d;
  asm volatile("global_load_dwordx4 %0, %1, off sc0 sc1" : "=v"(d) : "v"(addr));
  return d;
}
__device__ __forceinline__ void store4_sc(uint64_t addr, unsigned v) {
  asm volatile("global_store_dword %0, %1, off sc0 sc1" :: "v"(addr), "v"(v) : "memory");
}
#define WAITV(n) asm volatile("s_waitcnt vmcnt(" #n ")" ::: "memory")

// x[B][T][D] fp32 -> xb[T][B][D] bf16
__global__ void cvt_x(const float* __restrict__ x, u16* __restrict__ xb) {
  int i = blockIdx.x * 256 + threadIdx.x;
  int dblk = i & 63;
  int rest = i >> 6;
  int b = rest & 63;
  int t = rest >> 6;
  const float4* s = reinterpret_cast<const float4*>(x + ((size_t)(b * T_STEPS + t)) * DIN + dblk * 8);
  float4 f0 = s[0], f1 = s[1];
  uint4 o;
  o.x = (unsigned)f2bf(f0.x) | ((unsigned)f2bf(f0.y) << 16);
  o.y = (unsigned)f2bf(f0.z) | ((unsigned)f2bf(f0.w) << 16);
  o.z = (unsigned)f2bf(f1.x) | ((unsigned)f2bf(f1.y) << 16);
  o.w = (unsigned)f2bf(f1.z) | ((unsigned)f2bf(f1.w) << 16);
  *reinterpret_cast<uint4*>(xb + ((size_t)(t * BATCH + b)) * DIN + dblk * 8) = o;
}

// src f32 [K][4096] -> dst bf16 [4096 p][K], p = (gcol&1023)*4 + (gcol>>10).
__global__ void prep_t(const float* __restrict__ src, u16* __restrict__ dst, int K) {
  __shared__ u16 tl[64][72];   // [j][k] padded
  const int kb = blockIdx.x >> 6, cb = blockIdx.x & 63;
  const int tid = threadIdx.x;
  {
    const int kl = tid >> 2, j0 = (tid & 3) * 16;
    const float* s = src + (size_t)(kb * 64 + kl) * 4096 + cb * 64 + j0;
#pragma unroll
    for (int c = 0; c < 16; c += 4) {
      float4 v = *(const float4*)(s + c);
      tl[j0 + c + 0][kl] = f2bf(v.x);
      tl[j0 + c + 1][kl] = f2bf(v.y);
      tl[j0 + c + 2][kl] = f2bf(v.z);
      tl[j0 + c + 3][kl] = f2bf(v.w);
    }
  }
  __syncthreads();
  {
    const int j = tid >> 2, kp = (tid & 3) * 16;
    const int gcol = cb * 64 + j;
    const int p = (gcol & 1023) * 4 + (gcol >> 10);
    const uint4* s = (const uint4*)&tl[j][kp];
    uint4* d = (uint4*)(dst + (size_t)p * K + kb * 64 + kp);
    d[0] = s[0];
    d[1] = s[1];
  }
}

// Dual-chain persistent LSTM with SELF-VALIDATING TAGGED h (1 RT per phase).
// h word = bf16(h)<<16 | (step & 0xffff): dword-atomic, so data carries its
// own readiness flag. Publish = fire-and-forget per-thread dword stores;
// consume = load + tag-check + retry. 64 blocks, 8 waves = 8 exclusive
// K-splits; B-frags register-resident from pre-transposed upr/wpr.
__launch_bounds__(THREADS)
__global__ void lstm_kernel(const u16* __restrict__ upr, const u16* __restrict__ wpr,
                            const float* __restrict__ bias, const u16* __restrict__ xb,
                            char* __restrict__ ws, float* __restrict__ out) {
  __shared__ float zp[8][32][68];     // 69632 B

  const int tid = threadIdx.x;
  const int nb  = blockIdx.x;
  const int l   = tid & 63;
  const int wv  = tid >> 6;          // = K-split 0..7
  const int cl  = l & 31;
  const int q   = l >> 5;

  // ---- B fragments -> registers (coalesced b128 from pre-transposed bufs) ----
  bf16x8 ubf[2][8], wbf[2][4];
#pragma unroll
  for (int tile = 0; tile < 2; ++tile) {
    const u16* ub = upr + (size_t)(nb * 64 + tile * 32 + cl) * 1024 + wv * 128 + q * 8;
#pragma unroll
    for (int s = 0; s < 8; ++s) ubf[tile][s] = *(const bf16x8*)(ub + s * 16);
    const u16* wb = wpr + (size_t)(nb * 64 + tile * 32 + cl) * 512 + wv * 64 + q * 8;
#pragma unroll
    for (int s = 0; s < 4; ++s) wbf[tile][s] = *(const bf16x8*)(wb + s * 16);
  }

  // gate mapping: thread -> (row pb, unit pu)
  const int pb = tid & 31;
  const int pu = tid >> 5;           // 0..15
  const int j  = nb * UPB + pu;
  const float bi  = bias[j];
  const float bf_ = bias[1024 + j];
  const float bg  = bias[2048 + j];
  const float bo  = bias[3072 + j];
  float c0 = 0.f, c1 = 0.f;          // per-chain cell state (named, rule #20)

  const uint64_t thb = (uint64_t)ws + TH_OFF;
  // consumer base (per lane): row cl, units start ks*128 + q*8
  const uint64_t hoff = (uint64_t)cl * 4096 + (uint64_t)(wv * 128 + q * 8) * 4;
  // producer address (per thread): row pb, unit j
  const uint64_t poff = (uint64_t)pb * 4096 + (uint64_t)j * 4;

  for (int phase = 0; phase < 2 * T_STEPS; ++phase) {
    const int ch = phase & 1;
    const int t  = phase >> 1;
    const uint64_t hb  = thb + (uint64_t)ch * 262144 + (uint64_t)(t & 1) * 131072 + hoff;
    const unsigned etag = (unsigned)t & 0xffffu;

    // ---- x fragments (plain cached loads, issued first) ----
    bf16x8 xf[4];
    {
      const u16* xr = xb + ((size_t)(t * 64 + ch * 32 + cl)) * 512 + wv * 64 + q * 8;
#pragma unroll
      for (int s = 0; s < 4; ++s) xf[s] = *(const bf16x8*)(xr + s * 16);
    }

    // ---- issue 16 tagged-h loads (in flight across x-MFMAs) ----
    uint32x4 hbuf[16];
#pragma unroll
    for (int s = 0; s < 8; ++s) {
      hbuf[2 * s]     = load16_sc(hb + (uint64_t)s * 64);
      hbuf[2 * s + 1] = load16_sc(hb + (uint64_t)s * 64 + 16);
    }

    // ---- x_t @ W under the h RT: WAITV(16) drains xf + prior publish ----
    f32x16 acc0 = {0.f,0.f,0.f,0.f,0.f,0.f,0.f,0.f,0.f,0.f,0.f,0.f,0.f,0.f,0.f,0.f};
    f32x16 acc1 = {0.f,0.f,0.f,0.f,0.f,0.f,0.f,0.f,0.f,0.f,0.f,0.f,0.f,0.f,0.f,0.f};
    WAITV(16); __builtin_amdgcn_sched_barrier(0);
#pragma unroll
    for (int s = 0; s < 4; ++s) {
      acc0 = __builtin_amdgcn_mfma_f32_32x32x16_bf16(xf[s], wbf[0][s], acc0, 0, 0, 0);
      acc1 = __builtin_amdgcn_mfma_f32_32x32x16_bf16(xf[s], wbf[1][s], acc1, 0, 0, 0);
    }

    // ---- tag-check poll: data IS the flag; retry reloads all 16 ----
    while (true) {
      WAITV(0); __builtin_amdgcn_sched_barrier(0);
      unsigned bad = 0;
#pragma unroll
      for (int s = 0; s < 16; ++s) {
#pragma unroll
        for (int e = 0; e < 4; ++e) bad |= (hbuf[s][e] ^ etag) & 0xffffu;
      }
      if (__all(bad == 0)) break;
      __builtin_amdgcn_s_sleep(1);
#pragma unroll
      for (int s = 0; s < 8; ++s) {
        hbuf[2 * s]     = load16_sc(hb + (uint64_t)s * 64);
        hbuf[2 * s + 1] = load16_sc(hb + (uint64_t)s * 64 + 16);
      }
    }

    // ---- pack high16 -> bf16 fragments and h_t @ U ----
#pragma unroll
    for (int s = 0; s < 8; ++s) {
      uint32x4 d0 = hbuf[2 * s], d1 = hbuf[2 * s + 1];
      uint32x4 pk;
      pk[0] = (d0[0] >> 16) | (d0[1] & 0xffff0000u);
      pk[1] = (d0[2] >> 16) | (d0[3] & 0xffff0000u);
      pk[2] = (d1[0] >> 16) | (d1[1] & 0xffff0000u);
      pk[3] = (d1[2] >> 16) | (d1[3] & 0xffff0000u);
      bf16x8 a = __builtin_bit_cast(bf16x8, pk);
      acc0 = __builtin_amdgcn_mfma_f32_32x32x16_bf16(a, ubf[0][s], acc0, 0, 0, 0);
      acc1 = __builtin_amdgcn_mfma_f32_32x32x16_bf16(a, ubf[1][s], acc1, 0, 0, 0);
    }

    // ---- K-partials -> LDS (C layout: col=cl, row=(r&3)+8*(r>>2)+4*q) ----
#pragma unroll
    for (int r = 0; r < 16; ++r) {
      int rl = (r & 3) + 8 * (r >> 2) + 4 * q;
      zp[wv][rl][cl]      = acc0[r];
      zp[wv][rl][32 + cl] = acc1[r];
    }
    __syncthreads();

    // ---- gates + direct tagged publish (fire-and-forget) ----
    float zi = bi, zf = bf_, zg = bg, zo = bo;
#pragma unroll
    for (int k2 = 0; k2 < 8; ++k2) {
      float4 v = *(const float4*)&zp[k2][pb][pu * 4];
      zi += v.x; zf += v.y; zg += v.z; zo += v.w;
    }
    float ig = sigm(zi), fg = sigm(zf), og = sigm(zo);
    float gg = fast_tanh(zg);
    float cr = ch ? c1 : c0;
    cr = fg * cr + ig * gg;
    float h = og * fast_tanh(cr);
    if (ch) c1 = cr; else c0 = cr;
    unsigned tv = ((unsigned)f2bf(h) << 16) | ((unsigned)(t + 1) & 0xffffu);
    store4_sc(thb + (uint64_t)ch * 262144 + (uint64_t)((t + 1) & 1) * 131072 + poff, tv);
    if (t == T_STEPS - 1) {
      float* orow = out + (size_t)(ch * 32 + pb) * 3072 + j;
      orow[0]    = h;       // h_T
      orow[1024] = h;       // h_T again
      orow[2048] = cr;      // c_T
    }
    // NOTE: no second barrier — next phase's tag-poll can only pass after every
    // block's gate threads (which read zp this phase) published, so zp reuse is
    // transitively ordered by the tag protocol itself.
  }
}

extern "C" void kernel_launch(void* const* d_in, const int* in_sizes, int n_in,
                              void* d_out, int out_size, void* d_ws, size_t ws_size,
                              hipStream_t stream) {
  const float* x = (const float*)d_in[0];
  const float* W = (const float*)d_in[1];
  const float* U = (const float*)d_in[2];
  const float* b = (const float*)d_in[3];
  float* out = (float*)d_out;

  if (ws_size < WS_NEED) return;  // loud failure: output stays poisoned

  u16* xb  = (u16*)d_ws;
  u16* wpr = (u16*)((char*)d_ws + WPR_OFF);
  u16* upr = (u16*)((char*)d_ws + UPR_OFF);

  // zero tagged-h buffers (tag 0 == valid h_0 = 0) — replayed every launch
  hipMemsetAsync((char*)d_ws + TH_OFF, 0, TH_BYTES, stream);
  cvt_x<<<(T_STEPS * BATCH * DIN / 8 + 255) / 256, 256, 0, stream>>>(x, xb);
  prep_t<<<(512 / 64) * 64, 256, 0, stream>>>(W, wpr, 512);
  prep_t<<<(1024 / 64) * 64, 256, 0, stream>>>(U, upr, 1024);
  lstm_kernel<<<NBLK, THREADS, 0, stream>>>(upr, wpr, b, xb, (char*)d_ws, out);
}

// Round 13
// 6734.213 us; speedup vs baseline: 1.4719x; 1.4719x over previous
//
#include <hip/hip_runtime.h>
#include <stdint.h>

typedef unsigned short u16;

#define T_STEPS 512
#define BATCH   64
#define DIN     512
#define HID     1024
#define G4      4096
#define THREADS 512
#define NBLK    64      // 64 col-blocks, each owns 16 units (64 gate-cols)
#define UPB     16
// block col c = u_local*4 + gate  <->  gcol = gate*1024 + nb*16 + u_local
// pre-transposed weight row p = (gcol & 1023)*4 + (gcol >> 10) = nb*64 + c

// ws map
#define XB_BYTES  ((size_t)T_STEPS * BATCH * DIN * 2)     // 32 MB bf16 x
#define WPR_OFF   XB_BYTES                                // wpr bf16 [4096][512] = 4 MB
#define WPR_BYTES ((size_t)4096 * 512 * 2)
#define UPR_OFF   (WPR_OFF + WPR_BYTES)                   // upr bf16 [4096][1024] = 8 MB
#define UPR_BYTES ((size_t)4096 * 1024 * 2)
#define TH_OFF    (UPR_OFF + UPR_BYTES)                   // tagged h u32 [ch2][par2][row32][unit1024]
#define TH_BYTES  ((size_t)2 * 2 * 32 * 1024 * 4)         // 512 KB
#define FL_OFF    (TH_OFF + TH_BYTES)                     // flags [ch2][blk64], 64B stride
#define FL_BYTES  ((size_t)2 * 64 * 64)
#define WS_NEED   (FL_OFF + FL_BYTES)

typedef float f32x16 __attribute__((ext_vector_type(16)));
typedef short bf16x8 __attribute__((ext_vector_type(8)));
typedef unsigned uint32x4 __attribute__((ext_vector_type(4)));

__device__ __forceinline__ u16 f2bf(float f) {
  unsigned u = __float_as_uint(f);
  u += 0x7fffu + ((u >> 16) & 1u);   // RNE
  return (u16)(u >> 16);
}
__device__ __forceinline__ float sigm(float x) {
  return __builtin_amdgcn_rcpf(1.f + __expf(-x));
}
__device__ __forceinline__ float fast_tanh(float x) {
  return 1.f - 2.f * __builtin_amdgcn_rcpf(__expf(2.f * x) + 1.f);
}

// sc0 sc1 = coherence-point access (bypass L1/L2). Plain asm load keeps vmcnt
// ordering exact (compiler can't reorder volatile asm VMEM ops).
__device__ __forceinline__ uint32x4 load16_sc(uint64_t addr) {
  uint32x4 d;
  asm volatile("global_load_dwordx4 %0, %1, off sc0 sc1" : "=v"(d) : "v"(addr));
  return d;
}
__device__ __forceinline__ uint32x4 load16_plain(uint64_t addr) {
  uint32x4 d;
  asm volatile("global_load_dwordx4 %0, %1, off" : "=v"(d) : "v"(addr));
  return d;
}
__device__ __forceinline__ unsigned load4_sc(uint64_t addr) {
  unsigned d;
  asm volatile("global_load_dword %0, %1, off sc0 sc1" : "=v"(d) : "v"(addr));
  return d;
}
__device__ __forceinline__ void store4_sc(uint64_t addr, unsigned v) {
  asm volatile("global_store_dword %0, %1, off sc0 sc1" :: "v"(addr), "v"(v) : "memory");
}
#define WAITV(n) asm volatile("s_waitcnt vmcnt(" #n ")" ::: "memory")
#define SBAR()   __builtin_amdgcn_sched_barrier(0)

// x[B][T][D] fp32 -> xb[T][B][D] bf16
__global__ void cvt_x(const float* __restrict__ x, u16* __restrict__ xb) {
  int i = blockIdx.x * 256 + threadIdx.x;
  int dblk = i & 63;
  int rest = i >> 6;
  int b = rest & 63;
  int t = rest >> 6;
  const float4* s = reinterpret_cast<const float4*>(x + ((size_t)(b * T_STEPS + t)) * DIN + dblk * 8);
  float4 f0 = s[0], f1 = s[1];
  uint4 o;
  o.x = (unsigned)f2bf(f0.x) | ((unsigned)f2bf(f0.y) << 16);
  o.y = (unsigned)f2bf(f0.z) | ((unsigned)f2bf(f0.w) << 16);
  o.z = (unsigned)f2bf(f1.x) | ((unsigned)f2bf(f1.y) << 16);
  o.w = (unsigned)f2bf(f1.z) | ((unsigned)f2bf(f1.w) << 16);
  *reinterpret_cast<uint4*>(xb + ((size_t)(t * BATCH + b)) * DIN + dblk * 8) = o;
}

// src f32 [K][4096] -> dst bf16 [4096 p][K], p = (gcol&1023)*4 + (gcol>>10).
__global__ void prep_t(const float* __restrict__ src, u16* __restrict__ dst, int K) {
  __shared__ u16 tl[64][72];
  const int kb = blockIdx.x >> 6, cb = blockIdx.x & 63;
  const int tid = threadIdx.x;
  {
    const int kl = tid >> 2, j0 = (tid & 3) * 16;
    const float* s = src + (size_t)(kb * 64 + kl) * 4096 + cb * 64 + j0;
#pragma unroll
    for (int c = 0; c < 16; c += 4) {
      float4 v = *(const float4*)(s + c);
      tl[j0 + c + 0][kl] = f2bf(v.x);
      tl[j0 + c + 1][kl] = f2bf(v.y);
      tl[j0 + c + 2][kl] = f2bf(v.z);
      tl[j0 + c + 3][kl] = f2bf(v.w);
    }
  }
  __syncthreads();
  {
    const int j = tid >> 2, kp = (tid & 3) * 16;
    const int gcol = cb * 64 + j;
    const int p = (gcol & 1023) * 4 + (gcol >> 10);
    const uint4* s = (const uint4*)&tl[j][kp];
    uint4* d = (uint4*)(dst + (size_t)p * K + kb * 64 + kp);
    d[0] = s[0];
    d[1] = s[1];
  }
}

// Dual-chain persistent LSTM, tagged-h protocol (1 RT loop-carried chain).
// Tagged word = bf16(h)<<16 | step. Publish: gates -> LDS hst -> next phase
// COALESCED one-dword-per-thread stores (full 64B lines). Consume: speculative
// b128 loads + tag check; rare-miss fallback = flag poll (lazily certified)
// + single reload (protocol-fresh: a block stalled at step t hasn't published
// t+1, so no block anywhere can overwrite this parity buffer with tag t+2).
// 8 waves = 8 exclusive K-splits; B-frags register-resident.
__launch_bounds__(THREADS)
__global__ void lstm_kernel(const u16* __restrict__ upr, const u16* __restrict__ wpr,
                            const float* __restrict__ bias, const u16* __restrict__ xb,
                            char* __restrict__ ws, float* __restrict__ out) {
  __shared__ float zp[8][32][68];     // 69632 B
  __shared__ u16 hst[2][544];         // [ch][row*17 + u], padded

  const int tid = threadIdx.x;
  const int nb  = blockIdx.x;
  const int l   = tid & 63;
  const int wv  = tid >> 6;          // = K-split 0..7
  const int cl  = l & 31;
  const int q   = l >> 5;

  // ---- B fragments -> registers ----
  bf16x8 ubf[2][8], wbf[2][4];
#pragma unroll
  for (int tile = 0; tile < 2; ++tile) {
    const u16* ub = upr + (size_t)(nb * 64 + tile * 32 + cl) * 1024 + wv * 128 + q * 8;
#pragma unroll
    for (int s = 0; s < 8; ++s) ubf[tile][s] = *(const bf16x8*)(ub + s * 16);
    const u16* wb = wpr + (size_t)(nb * 64 + tile * 32 + cl) * 512 + wv * 64 + q * 8;
#pragma unroll
    for (int s = 0; s < 4; ++s) wbf[tile][s] = *(const bf16x8*)(wb + s * 16);
  }

  // init hst = 0 (phase-0 dummy publish re-writes memset content)
  for (int i = tid; i < 2 * 544; i += THREADS) ((u16*)hst)[i] = 0;

  // gate mapping: thread -> (row pb, unit pu)
  const int pb = tid & 31;
  const int pu = tid >> 5;
  const int j  = nb * UPB + pu;
  const float bi  = bias[j];
  const float bf_ = bias[1024 + j];
  const float bg  = bias[2048 + j];
  const float bo  = bias[3072 + j];
  float c0 = 0.f, c1 = 0.f;

  const uint64_t thb = (uint64_t)ws + TH_OFF;
  const uint64_t flg = (uint64_t)ws + FL_OFF;
  const uint64_t xb64 = (uint64_t)xb;
  // consumer lane base: row cl, units wv*128 + q*8
  const uint64_t hoff = (uint64_t)cl * 4096 + (uint64_t)(wv * 128 + q * 8) * 4;
  // publisher thread base: row tid>>4, unit nb*16 + (tid&15)
  const uint64_t puboffc = (uint64_t)(tid >> 4) * 4096 + (uint64_t)(nb * 16 + (tid & 15)) * 4;
  const int prow17 = (tid >> 4) * 17 + (tid & 15);

  __syncthreads();   // hst init visible

#define PACK8(A, D0, D1) do { uint32x4 pk_; \
    pk_[0] = (D0[0] >> 16) | (D0[1] & 0xffff0000u); \
    pk_[1] = (D0[2] >> 16) | (D0[3] & 0xffff0000u); \
    pk_[2] = (D1[0] >> 16) | (D1[1] & 0xffff0000u); \
    pk_[3] = (D1[2] >> 16) | (D1[3] & 0xffff0000u); \
    A = __builtin_bit_cast(bf16x8, pk_); } while (0)

  for (int phase = 0; phase < 2 * T_STEPS; ++phase) {
    const int ch = phase & 1;
    const int t  = phase >> 1;
    const unsigned etag = (unsigned)t;
    const int pch  = ch ^ 1;                 // previous phase's chain
    const int ptag = ((phase - 1) >> 1) + 1; // its published step tag
    const uint64_t hb = thb + (uint64_t)ch * 262144 + (uint64_t)(t & 1) * 131072 + hoff;

    // ---- issue: xf(4), hA(8), hB(8), pub(1) — exact vmcnt order ----
    uint32x4 xr0, xr1, xr2, xr3;
    {
      // lane k-base = wv*64 + q*8; subtile s advances k by 16 ELEMENTS = 32 B
      const uint64_t xa = xb64 + ((uint64_t)(t * 64 + ch * 32 + cl) * 512 + wv * 64 + q * 8) * 2;
      xr0 = load16_plain(xa);
      xr1 = load16_plain(xa + 32);
      xr2 = load16_plain(xa + 64);
      xr3 = load16_plain(xa + 96);
    }
    uint32x4 hA[8], hB[8];
#pragma unroll
    for (int s = 0; s < 4; ++s) {
      hA[2 * s]     = load16_sc(hb + (uint64_t)s * 64);
      hA[2 * s + 1] = load16_sc(hb + (uint64_t)s * 64 + 16);
    }
#pragma unroll
    for (int s = 4; s < 8; ++s) {
      hB[2 * (s - 4)]     = load16_sc(hb + (uint64_t)s * 64);
      hB[2 * (s - 4) + 1] = load16_sc(hb + (uint64_t)s * 64 + 16);
    }
    {  // coalesced tagged publish of prev phase's h (full 64B lines)
      unsigned hv = (unsigned)hst[pch][prow17];
      unsigned pv = (hv << 16) | (unsigned)(ptag & 0xffff);
      uint64_t pa = thb + (uint64_t)pch * 262144 + (uint64_t)(ptag & 1) * 131072 + puboffc;
      store4_sc(pa, pv);
    }

    // ---- x_t @ W under the h RT ----
    f32x16 acc0 = {0.f,0.f,0.f,0.f,0.f,0.f,0.f,0.f,0.f,0.f,0.f,0.f,0.f,0.f,0.f,0.f};
    f32x16 acc1 = {0.f,0.f,0.f,0.f,0.f,0.f,0.f,0.f,0.f,0.f,0.f,0.f,0.f,0.f,0.f,0.f};
    WAITV(17); SBAR();
    {
      bf16x8 x0 = __builtin_bit_cast(bf16x8, xr0), x1 = __builtin_bit_cast(bf16x8, xr1);
      bf16x8 x2 = __builtin_bit_cast(bf16x8, xr2), x3 = __builtin_bit_cast(bf16x8, xr3);
      acc0 = __builtin_amdgcn_mfma_f32_32x32x16_bf16(x0, wbf[0][0], acc0, 0, 0, 0);
      acc1 = __builtin_amdgcn_mfma_f32_32x32x16_bf16(x0, wbf[1][0], acc1, 0, 0, 0);
      acc0 = __builtin_amdgcn_mfma_f32_32x32x16_bf16(x1, wbf[0][1], acc0, 0, 0, 0);
      acc1 = __builtin_amdgcn_mfma_f32_32x32x16_bf16(x1, wbf[1][1], acc1, 0, 0, 0);
      acc0 = __builtin_amdgcn_mfma_f32_32x32x16_bf16(x2, wbf[0][2], acc0, 0, 0, 0);
      acc1 = __builtin_amdgcn_mfma_f32_32x32x16_bf16(x2, wbf[1][2], acc1, 0, 0, 0);
      acc0 = __builtin_amdgcn_mfma_f32_32x32x16_bf16(x3, wbf[0][3], acc0, 0, 0, 0);
      acc1 = __builtin_amdgcn_mfma_f32_32x32x16_bf16(x3, wbf[1][3], acc1, 0, 0, 0);
    }

    // ---- half A: tag-check, fallback-once, MFMA ----
    WAITV(9); SBAR();
    {
      unsigned bad = 0;
#pragma unroll
      for (int s = 0; s < 8; ++s) {
#pragma unroll
        for (int e = 0; e < 4; ++e) bad |= (hA[s][e] ^ etag) & 0xffffu;
      }
      if (!__all(bad == 0)) {
        const uint64_t fa = flg + (uint64_t)(ch * 64 + wv * 8 + (l & 3)) * 64;
        while (true) {
          unsigned f = load4_sc(fa);
          WAITV(0);
          if (__all(f >= etag)) break;
          __builtin_amdgcn_s_sleep(8);
        }
#pragma unroll
        for (int s = 0; s < 4; ++s) {
          hA[2 * s]     = load16_sc(hb + (uint64_t)s * 64);
          hA[2 * s + 1] = load16_sc(hb + (uint64_t)s * 64 + 16);
        }
        WAITV(0); SBAR();
      }
    }
#pragma unroll
    for (int s = 0; s < 4; ++s) {
      bf16x8 a; PACK8(a, hA[2 * s], hA[2 * s + 1]);
      acc0 = __builtin_amdgcn_mfma_f32_32x32x16_bf16(a, ubf[0][s], acc0, 0, 0, 0);
      acc1 = __builtin_amdgcn_mfma_f32_32x32x16_bf16(a, ubf[1][s], acc1, 0, 0, 0);
    }

    // ---- half B ----
    WAITV(1); SBAR();
    {
      unsigned bad = 0;
#pragma unroll
      for (int s = 0; s < 8; ++s) {
#pragma unroll
        for (int e = 0; e < 4; ++e) bad |= (hB[s][e] ^ etag) & 0xffffu;
      }
      if (!__all(bad == 0)) {
        const uint64_t fa = flg + (uint64_t)(ch * 64 + wv * 8 + 4 + (l & 3)) * 64;
        while (true) {
          unsigned f = load4_sc(fa);
          WAITV(0);
          if (__all(f >= etag)) break;
          __builtin_amdgcn_s_sleep(8);
        }
#pragma unroll
        for (int s = 4; s < 8; ++s) {
          hB[2 * (s - 4)]     = load16_sc(hb + (uint64_t)s * 64);
          hB[2 * (s - 4) + 1] = load16_sc(hb + (uint64_t)s * 64 + 16);
        }
        WAITV(0); SBAR();
      }
    }
#pragma unroll
    for (int s = 4; s < 8; ++s) {
      bf16x8 a; PACK8(a, hB[2 * (s - 4)], hB[2 * (s - 4) + 1]);
      acc0 = __builtin_amdgcn_mfma_f32_32x32x16_bf16(a, ubf[0][s], acc0, 0, 0, 0);
      acc1 = __builtin_amdgcn_mfma_f32_32x32x16_bf16(a, ubf[1][s], acc1, 0, 0, 0);
    }

    // ---- K-partials -> LDS ----
#pragma unroll
    for (int r = 0; r < 16; ++r) {
      int rl = (r & 3) + 8 * (r >> 2) + 4 * q;
      zp[wv][rl][cl]      = acc0[r];
      zp[wv][rl][32 + cl] = acc1[r];
    }
    WAITV(0);          // pub store acked (issued ~RT ago — nearly free)
    __syncthreads();   // zp complete + all waves' pub stores acked

    // lazy flag certification for the publish stored THIS phase
    if (tid == 0) store4_sc(flg + (uint64_t)(pch * 64 + nb) * 64, (unsigned)ptag);

    // ---- gates ----
    float zi = bi, zf = bf_, zg = bg, zo = bo;
#pragma unroll
    for (int k2 = 0; k2 < 8; ++k2) {
      float4 v = *(const float4*)&zp[k2][pb][pu * 4];
      zi += v.x; zf += v.y; zg += v.z; zo += v.w;
    }
    float ig = sigm(zi), fg = sigm(zf), og = sigm(zo);
    float gg = fast_tanh(zg);
    float cr = ch ? c1 : c0;
    cr = fg * cr + ig * gg;
    float h = og * fast_tanh(cr);
    if (ch) c1 = cr; else c0 = cr;
    hst[ch][pb * 17 + pu] = f2bf(h);
    if (t == T_STEPS - 1) {
      float* orow = out + (size_t)(ch * 32 + pb) * 3072 + j;
      orow[0]    = h;       // h_T
      orow[1024] = h;       // h_T again
      orow[2048] = cr;      // c_T
    }
    __syncthreads();   // hst[ch] complete; zp reads done
  }
#undef PACK8
}

extern "C" void kernel_launch(void* const* d_in, const int* in_sizes, int n_in,
                              void* d_out, int out_size, void* d_ws, size_t ws_size,
                              hipStream_t stream) {
  const float* x = (const float*)d_in[0];
  const float* W = (const float*)d_in[1];
  const float* U = (const float*)d_in[2];
  const float* b = (const float*)d_in[3];
  float* out = (float*)d_out;

  if (ws_size < WS_NEED) return;  // loud failure: output stays poisoned

  u16* xb  = (u16*)d_ws;
  u16* wpr = (u16*)((char*)d_ws + WPR_OFF);
  u16* upr = (u16*)((char*)d_ws + UPR_OFF);

  // zero tagged-h (tag 0 == valid h_0 = 0) + flags — replayed every launch
  hipMemsetAsync((char*)d_ws + TH_OFF, 0, TH_BYTES + FL_BYTES, stream);
  cvt_x<<<(T_STEPS * BATCH * DIN / 8 + 255) / 256, 256, 0, stream>>>(x, xb);
  prep_t<<<(512 / 64) * 64, 256, 0, stream>>>(W, wpr, 512);
  prep_t<<<(1024 / 64) * 64, 256, 0, stream>>>(U, upr, 1024);
  lstm_kernel<<<NBLK, THREADS, 0, stream>>>(upr, wpr, b, xb, (char*)d_ws, out);
}

// Round 14
// 2583.735 us; speedup vs baseline: 3.8364x; 2.6064x over previous
//
#include <hip/hip_runtime.h>
#include <stdint.h>

typedef unsigned short u16;

#define T_STEPS 512
#define BATCH   64
#define DIN     512
#define HID     1024
#define G4      4096
#define NBLK    128
#define NH      8       // hidden units per block
#define NC      32      // gate columns per block (4*NH)
#define THREADS 512

#define U_LD    1032    // 1024 + 8 pad (init staging only)
#define W_LD    520     // 512 + 8 pad  (init staging only)

// LDS: init phase  Ut[NC*U_LD] @0 (66048B), Wt[NC*W_LD] @66048 (33280B)
//      run  phase  zpart f32[4][64][33] @0 (33792B)
#define SM_BYTES 99328
#define WT_OFF   66048

// ws map
#define XB_BYTES ((size_t)T_STEPS * BATCH * DIN * 2)   // 32 MB bf16 x
#define HB_OFF   XB_BYTES                              // h: [parity][kblk128][row64][8u] bf16
#define HB_BYTES (2u * BATCH * HID * 2)                // 256 KB
#define FLG_OFF  (HB_OFF + HB_BYTES)                   // 128 flags x 16B
#define FLG_BYTES 2048
#define WS_NEED  (FLG_OFF + FLG_BYTES)

typedef float f32x16 __attribute__((ext_vector_type(16)));
typedef short bf16x8 __attribute__((ext_vector_type(8)));
typedef unsigned uint32x4 __attribute__((ext_vector_type(4)));

__device__ __forceinline__ u16 f2bf(float f) {
  unsigned u = __float_as_uint(f);
  u += 0x7fffu + ((u >> 16) & 1u);   // RNE
  return (u16)(u >> 16);
}
__device__ __forceinline__ float sigm(float x) {
  return __builtin_amdgcn_rcpf(1.f + __expf(-x));
}
__device__ __forceinline__ float fast_tanh(float x) {
  return 1.f - 2.f * __builtin_amdgcn_rcpf(__expf(2.f * x) + 1.f);
}

// Coherent (L2-bypass, served at coherence point) helpers; flat 64b VGPR addr.
__device__ __forceinline__ uint32x4 load16_sc(uint64_t addr) {
  uint32x4 d;
  asm volatile("global_load_dwordx4 %0, %1, off sc0 sc1" : "=v"(d) : "v"(addr));
  return d;
}
__device__ __forceinline__ unsigned load4_sc(uint64_t addr) {
  unsigned d;
  asm volatile("global_load_dword %0, %1, off sc0 sc1" : "=v"(d) : "v"(addr));
  return d;
}
__device__ __forceinline__ void store16_sc(uint64_t addr, uint32x4 v) {
  asm volatile("global_store_dwordx4 %0, %1, off sc0 sc1" :: "v"(addr), "v"(v) : "memory");
}
__device__ __forceinline__ void store4_sc(uint64_t addr, unsigned v) {
  asm volatile("global_store_dword %0, %1, off sc0 sc1" :: "v"(addr), "v"(v) : "memory");
}
#define WAITV(n) asm volatile("s_waitcnt vmcnt(" #n ")" ::: "memory")

// x[B][T][D] fp32 -> xb[T][B][D] bf16
__global__ void cvt_x(const float* __restrict__ x, u16* __restrict__ xb) {
  int i = blockIdx.x * 256 + threadIdx.x;
  int dblk = i & 63;
  int rest = i >> 6;
  int b = rest & 63;
  int t = rest >> 6;
  const float4* s = reinterpret_cast<const float4*>(x + ((size_t)(b * T_STEPS + t)) * DIN + dblk * 8);
  float4 f0 = s[0], f1 = s[1];
  uint4 o;
  o.x = (unsigned)f2bf(f0.x) | ((unsigned)f2bf(f0.y) << 16);
  o.y = (unsigned)f2bf(f0.z) | ((unsigned)f2bf(f0.w) << 16);
  o.z = (unsigned)f2bf(f1.x) | ((unsigned)f2bf(f1.y) << 16);
  o.w = (unsigned)f2bf(f1.z) | ((unsigned)f2bf(f1.w) << 16);
  *reinterpret_cast<uint4*>(xb + ((size_t)(t * BATCH + b)) * DIN + dblk * 8) = o;
}

// Persistent LSTM (r6 structure). Block bid owns hidden units [bid*8, bid*8+8).
// GEMM: 32x32x16 MFMA, 8 waves = 2 M-tiles x 4 K-splits; B-frags in registers;
// K-split partials reduced through LDS (zp). h layout [kblk=128][b=64][8] bf16.
// Wave ks polls ONLY its 32 producer flags. NEW vs r6: publish is in-register
// packed (shfl) and issued by ALL 8 waves in parallel (8x16B leaders each) --
// no LDS hstage, no wave0-only store serialization; acks overlap across waves.
__launch_bounds__(THREADS)
__global__ void lstm_kernel(const float* __restrict__ W, const float* __restrict__ U,
                            const float* __restrict__ bias, const u16* __restrict__ xb,
                            u16* __restrict__ hbuf, float* __restrict__ out,
                            unsigned* __restrict__ flags) {
  __shared__ __align__(16) char smraw[SM_BYTES];
  u16* Ut = (u16*)smraw;
  u16* Wt = (u16*)(smraw + WT_OFF);
  float* zp = (float*)smraw;              // run phase: [4][64][33]

  const int tid = threadIdx.x;
  const int bid = blockIdx.x;
  const int j0 = bid * NH;

  // ---- init: stage transposed bf16 weight slices ----
  for (int idx = tid; idx < NC * HID; idx += THREADS) {
    int c = idx & (NC - 1);
    int k = idx >> 5;
    int gcol = ((c >> 3) << 10) + j0 + (c & 7);
    Ut[c * U_LD + k] = f2bf(U[(size_t)k * G4 + gcol]);
  }
  for (int idx = tid; idx < NC * DIN; idx += THREADS) {
    int c = idx & (NC - 1);
    int k = idx >> 5;
    int gcol = ((c >> 3) << 10) + j0 + (c & 7);
    Wt[c * W_LD + k] = f2bf(W[(size_t)k * G4 + gcol]);
  }
  __syncthreads();

  // ---- wave geometry: wv = (ks<<1)|m_t ----
  const int l   = tid & 63;
  const int wv  = tid >> 6;
  const int m_t = wv & 1;          // batch rows m_t*32 .. +31
  const int ks  = wv >> 1;         // K-split 0..3 (256 of HID, 128 of DIN each)
  const int cl  = l & 31;          // A row within tile / B column
  const int q   = l >> 5;          // k-half of fragment

  // ---- persistent B fragments -> registers ----
  bf16x8 ubf[16], wbf[8];
  {
    const u16* ub = Ut + cl * U_LD + ks * 256 + q * 8;
#pragma unroll
    for (int s = 0; s < 16; ++s) ubf[s] = *(const bf16x8*)(ub + s * 16);
    const u16* wb = Wt + cl * W_LD + ks * 128 + q * 8;
#pragma unroll
    for (int s = 0; s < 8; ++s) wbf[s] = *(const bf16x8*)(wb + s * 16);
  }
  __syncthreads();   // staging dead; zp live from here

  const int row = m_t * 32 + cl;   // batch row this lane loads for A
  // gates: thread -> (row pb, unit pu); pu in low bits so a wave's 64 lanes
  // cover 8 consecutive rows x 8 units = one contiguous 128B publish slice
  const int pb = tid >> 3;
  const int pu = tid & 7;
  float c_reg = 0.f;
  const float bi  = bias[j0 + pu];
  const float bf_ = bias[1024 + j0 + pu];
  const float bg  = bias[2048 + j0 + pu];
  const float bo  = bias[3072 + j0 + pu];

  const uint64_t fbase = (uint64_t)flags;
  // per-lane poll address: the ONE producer flag this lane's wave-k-slice needs
  const uint64_t faddr = fbase + (uint64_t)(ks * 32 + cl) * 16;
  // h A-frag: kblk = ks*32 + s*2 + q, byte = kblk*1024 + row*16
  const uint64_t hlane = (uint64_t)(ks * 32 + q) * 1024 + (uint64_t)row * 16;
  // publish: leader lanes (l&7)==0 store 16B of row wv*8 + (l>>3)
  const uint64_t puboff = (uint64_t)bid * 1024 + (uint64_t)(wv * 8 + (l >> 3)) * 16;

#define HMFMA(S) acc = __builtin_amdgcn_mfma_f32_32x32x16_bf16( \
    __builtin_bit_cast(bf16x8, abuf[S]), ubf[S], acc, 0, 0, 0)

  for (int t = 0; t < T_STEPS; ++t) {
    f32x16 acc = {0.f,0.f,0.f,0.f,0.f,0.f,0.f,0.f,0.f,0.f,0.f,0.f,0.f,0.f,0.f,0.f};

    // ---- x_t @ W (cached loads; overlaps other blocks finishing t-1) ----
    const u16* xa = xb + (size_t)t * (BATCH * DIN) + row * DIN + ks * 128 + q * 8;
#pragma unroll
    for (int s = 0; s < 8; ++s) {
      bf16x8 av = *(const bf16x8*)(xa + s * 16);
      acc = __builtin_amdgcn_mfma_f32_32x32x16_bf16(av, wbf[s], acc, 0, 0, 0);
    }

    // ---- fine-grained poll: one flag per lane, this wave's 32 producers ----
    while (true) {
      unsigned f = load4_sc(faddr);
      WAITV(0);
      if (__all(f >= (unsigned)t)) break;
      __builtin_amdgcn_s_sleep(1);
    }

    // ---- h_t @ U: 16 sc1 loads in flight, counted vmcnt ----
    const uint64_t hb = (uint64_t)hbuf + (uint64_t)(t & 1) * (BATCH * HID * 2) + hlane;
    uint32x4 abuf[16];
#pragma unroll
    for (int s = 0; s < 16; ++s) abuf[s] = load16_sc(hb + (uint64_t)s * 2048);
    WAITV(12); __builtin_amdgcn_sched_barrier(0);
    HMFMA(0); HMFMA(1); HMFMA(2); HMFMA(3);
    WAITV(8); __builtin_amdgcn_sched_barrier(0);
    HMFMA(4); HMFMA(5); HMFMA(6); HMFMA(7);
    WAITV(4); __builtin_amdgcn_sched_barrier(0);
    HMFMA(8); HMFMA(9); HMFMA(10); HMFMA(11);
    WAITV(0); __builtin_amdgcn_sched_barrier(0);
    HMFMA(12); HMFMA(13); HMFMA(14); HMFMA(15);

    // ---- K-split partial -> LDS (C layout: col=l&31, row=(r&3)+8*(r>>2)+4*q) ----
#pragma unroll
    for (int r = 0; r < 16; ++r) {
      int rl = (r & 3) + 8 * (r >> 2) + 4 * q;
      zp[ks * 2112 + (m_t * 32 + rl) * 33 + cl] = acc[r];
    }
    __syncthreads();

    // ---- reduce partials + gates: one thread per (batch, unit) ----
    float zi = bi, zf = bf_, zg = bg, zo = bo;
#pragma unroll
    for (int k2 = 0; k2 < 4; ++k2) {
      const float* zr = zp + k2 * 2112 + pb * 33;
      zi += zr[pu]; zf += zr[pu + 8]; zg += zr[pu + 16]; zo += zr[pu + 24];
    }
    float ig = sigm(zi), fg = sigm(zf), og = sigm(zo);
    float gg = fast_tanh(zg);
    c_reg = fg * c_reg + ig * gg;
    float h = og * fast_tanh(c_reg);

    // ---- in-register pack: 8 lanes' u16 h -> 16B on leader lanes ----
    unsigned hval = (unsigned)f2bf(h);
    unsigned other = __shfl_xor(hval, 1);
    unsigned pair32 = (l & 1) ? ((other & 0xffffu) | (hval << 16))
                              : ((hval & 0xffffu) | (other << 16));
    int base = l & ~7;
    uint32x4 hv;
    hv[0] = __shfl(pair32, base);
    hv[1] = __shfl(pair32, base + 2);
    hv[2] = __shfl(pair32, base + 4);
    hv[3] = __shfl(pair32, base + 6);

    // ---- publish h_{t+1}: every wave stores its 128B slice in parallel ----
    const uint64_t hbn = (uint64_t)hbuf + (uint64_t)((t + 1) & 1) * (BATCH * HID * 2);
    if ((l & 7) == 0) store16_sc(hbn + puboff, hv);
    if (t == T_STEPS - 1) {
      float* orow = out + (size_t)pb * 3072 + j0 + pu;
      orow[0]    = h;       // h_T
      orow[1024] = h;       // h_T again
      orow[2048] = c_reg;   // c_T
    }
    WAITV(0);          // ack this wave's publish (and epilogue stores, last step)
    __syncthreads();   // all waves acked; zp reads done
    if (tid == 0) store4_sc(fbase + (uint64_t)bid * 16, (unsigned)(t + 1));
  }
#undef HMFMA
}

extern "C" void kernel_launch(void* const* d_in, const int* in_sizes, int n_in,
                              void* d_out, int out_size, void* d_ws, size_t ws_size,
                              hipStream_t stream) {
  const float* x = (const float*)d_in[0];
  const float* W = (const float*)d_in[1];
  const float* U = (const float*)d_in[2];
  const float* b = (const float*)d_in[3];
  float* out = (float*)d_out;

  if (ws_size < WS_NEED) return;  // loud failure: output stays poisoned

  u16* xb         = (u16*)d_ws;
  u16* hbuf       = (u16*)((char*)d_ws + HB_OFF);
  unsigned* flags = (unsigned*)((char*)d_ws + FLG_OFF);

  // zero h0 (both parities) + flags — replayed every graph launch
  hipMemsetAsync((void*)hbuf, 0, HB_BYTES + FLG_BYTES, stream);
  cvt_x<<<(T_STEPS * BATCH * DIN / 8 + 255) / 256, 256, 0, stream>>>(x, xb);
  lstm_kernel<<<NBLK, THREADS, 0, stream>>>(W, U, b, xb, hbuf, out, flags);
}